// Round 3
// baseline (613.482 us; speedup 1.0000x reference)
//
#include <hip/hip_runtime.h>
#include <hip/hip_bf16.h>

typedef unsigned short u16;
typedef __attribute__((ext_vector_type(8))) short bf16x8;
typedef __attribute__((ext_vector_type(4))) float f32x4;
typedef __attribute__((ext_vector_type(4))) unsigned short u16x4;

#define DEVI static __device__ __forceinline__

DEVI u16 f2bf(float f) {
    union { __hip_bfloat16 h; u16 u; } cv;
    cv.h = __float2bfloat16(f);
    return cv.u;
}
DEVI float bf2f(u16 u) {
    union { u16 u; __hip_bfloat16 h; } cv;
    cv.u = u;
    return __bfloat162float(cv.h);
}

DEVI void gload_lds16(const void* g, void* l) {
    __builtin_amdgcn_global_load_lds(
        (const __attribute__((address_space(1))) unsigned int*)g,
        (__attribute__((address_space(3))) unsigned int*)l, 16, 0, 0);
}

// ---------------- convert f32 -> bf16 (vectorized) ----------------
__global__ void k_cvt(const float* __restrict__ in, u16* __restrict__ out, int n4) {
    int i = blockIdx.x * blockDim.x + threadIdx.x;
    int stride = gridDim.x * blockDim.x;
    for (; i < n4; i += stride) {
        float4 v = ((const float4*)in)[i];
        u16x4 o;
        o.x = f2bf(v.x); o.y = f2bf(v.y); o.z = f2bf(v.z); o.w = f2bf(v.w);
        ((u16x4*)out)[i] = o;
    }
}

// ---------------- rope cos/sin table [4096][32] float2 ----------------
__global__ void k_rope(float2* __restrict__ tab) {
    int i = blockIdx.x * 256 + threadIdx.x;   // 0..131071
    int t = i >> 5, j = i & 31;
    float inv = powf(10000.f, -(float)j / 32.f);
    float ang = (float)t * inv;
    float s, c;
    sincosf(ang, &s, &c);
    tab[i] = make_float2(c, s);
}

// ---------------- GEMM: C[M,N] = A[M,1024] @ Bw[N,1024]^T ----------------
// MODE 0: KV gemm. A rows are "selected" indices s in [0,16384): remapped to x rows.
//         cols<1024 get RoPE, store bf16 into kv[s*2048+col].
// MODE 1: logits gemm, store bf16 [row*1024+col].
// MODE 2: out gemm, store f32 [row*1024+col].
template<int MODE>
__global__ __launch_bounds__(256, 2) void k_gemm(
    const u16* __restrict__ A, const u16* __restrict__ Bw,
    void* __restrict__ Cout, const float2* __restrict__ rope)
{
    constexpr int K = 1024;
    __shared__ u16 As[128 * 32];
    __shared__ u16 Bs[128 * 32];
    const int tid = threadIdx.x;
    const int lane = tid & 63, wid = tid >> 6;
    const int wr = wid >> 1, wc = wid & 1;
    const int row0 = blockIdx.y * 128, col0 = blockIdx.x * 128;

    int r0 = row0 + (tid >> 2);
    int r1 = r0 + 64;
    if (MODE == 0) {  // selected row -> x row: b*4096 + n*128 + c
        r0 = ((r0 >> 11) << 12) | (((r0 >> 6) & 31) << 7) | (r0 & 63);
        r1 = ((r1 >> 11) << 12) | (((r1 >> 6) & 31) << 7) | (r1 & 63);
    }
    const int kcol = (tid & 3) * 8;
    const u16* gA0 = A + (size_t)r0 * K + kcol;
    const u16* gA1 = A + (size_t)r1 * K + kcol;
    const u16* gB0 = Bw + (size_t)(col0 + (tid >> 2)) * K + kcol;
    const u16* gB1 = gB0 + (size_t)64 * K;

    char* AsB = (char*)As + wid * 1024;
    char* BsB = (char*)Bs + wid * 1024;

    f32x4 acc[4][4];
#pragma unroll
    for (int i = 0; i < 4; ++i)
#pragma unroll
        for (int j = 0; j < 4; ++j) acc[i][j] = f32x4{0.f, 0.f, 0.f, 0.f};

#pragma unroll 1
    for (int kt = 0; kt < K / 32; ++kt) {
        gload_lds16(gA0, AsB);
        gload_lds16(gA1, AsB + 4096);
        gload_lds16(gB0, BsB);
        gload_lds16(gB1, BsB + 4096);
        gA0 += 32; gA1 += 32; gB0 += 32; gB1 += 32;
        __syncthreads();
        const int koff = (lane >> 4) * 8;
        bf16x8 af[4], bfr[4];
#pragma unroll
        for (int mf = 0; mf < 4; ++mf)
            af[mf] = *(const bf16x8*)&As[(wr * 64 + mf * 16 + (lane & 15)) * 32 + koff];
#pragma unroll
        for (int nf = 0; nf < 4; ++nf)
            bfr[nf] = *(const bf16x8*)&Bs[(wc * 64 + nf * 16 + (lane & 15)) * 32 + koff];
#pragma unroll
        for (int mf = 0; mf < 4; ++mf)
#pragma unroll
            for (int nf = 0; nf < 4; ++nf)
                acc[mf][nf] = __builtin_amdgcn_mfma_f32_16x16x32_bf16(af[mf], bfr[nf], acc[mf][nf], 0, 0, 0);
        __syncthreads();
    }

    const int rbase = row0 + wr * 64 + (lane >> 4) * 4;
    const int cbase = col0 + wc * 64 + (lane & 15);
#pragma unroll
    for (int mf = 0; mf < 4; ++mf) {
#pragma unroll
        for (int nf = 0; nf < 4; ++nf) {
            const int gc = cbase + nf * 16;
#pragma unroll
            for (int r = 0; r < 4; ++r) {
                const int gr = rbase + mf * 16 + r;
                float v = acc[mf][nf][r];
                if (MODE == 0) {
                    float o = __shfl_xor(v, 1);
                    float res;
                    if (gc < 1024) {  // k with rope (uniform per block: col tiles of 128)
                        int t = (((gr >> 6) & 31) << 7) | (gr & 63);
                        float2 cs = rope[t * 32 + ((gc & 63) >> 1)];
                        res = (gc & 1) ? (o * cs.y + v * cs.x) : (v * cs.x - o * cs.y);
                    } else {
                        res = v;
                    }
                    ((u16*)Cout)[(size_t)gr * 2048 + gc] = f2bf(res);
                } else if (MODE == 1) {
                    ((u16*)Cout)[(size_t)gr * 1024 + gc] = f2bf(v);
                } else {
                    ((float*)Cout)[(size_t)gr * 1024 + gc] = v;
                }
            }
        }
    }
}

// ---------------- attention: per (b,h) accumulate attnT[d][l] ----------------
// grid = B*H*4; block 256 = 4 waves; wave handles 2 chunks (of 32).
__global__ __launch_bounds__(256, 2) void k_attn(
    const u16* __restrict__ kv, const float* __restrict__ lq, float* __restrict__ attnT)
{
    __shared__ char smem[65536];
    const int tid = threadIdx.x;
    const int lane = tid & 63, wid = tid >> 6;
    const int gidx = blockIdx.x & 3;
    const int bh = blockIdx.x >> 2;
    const int b = bh >> 4, h = bh & 15;

    // q fragments (A operand of QK^T), scale 1/8 folded in. q[l][d] = lq[(l*16+h)*64+d]
    bf16x8 qf[4][2];
#pragma unroll
    for (int lb = 0; lb < 4; ++lb)
#pragma unroll
        for (int kb = 0; kb < 2; ++kb) {
            const float* src = lq + ((size_t)(lb * 16 + (lane & 15)) * 16 + h) * 64 + kb * 32 + (lane >> 4) * 8;
            float4 v0 = ((const float4*)src)[0];
            float4 v1 = ((const float4*)src)[1];
            union { bf16x8 v; u16 u[8]; } pk;
            pk.u[0] = f2bf(v0.x * 0.125f); pk.u[1] = f2bf(v0.y * 0.125f);
            pk.u[2] = f2bf(v0.z * 0.125f); pk.u[3] = f2bf(v0.w * 0.125f);
            pk.u[4] = f2bf(v1.x * 0.125f); pk.u[5] = f2bf(v1.y * 0.125f);
            pk.u[6] = f2bf(v1.z * 0.125f); pk.u[7] = f2bf(v1.w * 0.125f);
            qf[lb][kb] = pk.v;
        }

    char* Pl = smem + wid * 16384;            // P tile [64][64] bf16, XOR-swizzled
    char* Vb = smem + wid * 16384 + 8192;     // V tile [64][64] bf16, linear
    u16* Vl = (u16*)Vb;

    f32x4 accT[4][4];
#pragma unroll
    for (int i = 0; i < 4; ++i)
#pragma unroll
        for (int j = 0; j < 4; ++j) accT[i][j] = f32x4{0.f, 0.f, 0.f, 0.f};

#pragma unroll 1
    for (int ci = 0; ci < 2; ++ci) {
        const int n = gidx * 8 + wid * 2 + ci;
        const size_t krow = (size_t)b * 2048 + (size_t)n * 64;

        // stage V chunk -> LDS (linear [c][d]) while QK^T runs
#pragma unroll
        for (int j = 0; j < 8; ++j) {
            const u16* g = kv + (krow + j * 8 + (lane >> 3)) * 2048 + 1024 + h * 64 + (lane & 7) * 8;
            gload_lds16(g, Vb + j * 1024);
        }

        // QK^T: S[l][c]
        f32x4 S[4][4];
#pragma unroll
        for (int i = 0; i < 4; ++i)
#pragma unroll
            for (int j = 0; j < 4; ++j) S[i][j] = f32x4{0.f, 0.f, 0.f, 0.f};
#pragma unroll
        for (int kb = 0; kb < 2; ++kb) {
            bf16x8 kf[4];
#pragma unroll
            for (int cb = 0; cb < 4; ++cb)
                kf[cb] = *(const bf16x8*)(kv + (krow + cb * 16 + (lane & 15)) * 2048 + h * 64 + kb * 32 + (lane >> 4) * 8);
#pragma unroll
            for (int lb = 0; lb < 4; ++lb)
#pragma unroll
                for (int cb = 0; cb < 4; ++cb)
                    S[lb][cb] = __builtin_amdgcn_mfma_f32_16x16x32_bf16(qf[lb][kb], kf[cb], S[lb][cb], 0, 0, 0);
        }

        // masked softmax over c, write P (bf16) to LDS swizzled
#pragma unroll
        for (int lb = 0; lb < 4; ++lb) {
#pragma unroll
            for (int r = 0; r < 4; ++r) {
                const int l = lb * 16 + (lane >> 4) * 4 + r;
                const int c0 = lane & 15;
                float vv[4];
                float m = -3e30f;
#pragma unroll
                for (int cb = 0; cb < 4; ++cb) {
                    int c = cb * 16 + c0;
                    vv[cb] = (c <= l) ? S[lb][cb][r] : -3e30f;
                    m = fmaxf(m, vv[cb]);
                }
                m = fmaxf(m, __shfl_xor(m, 1));
                m = fmaxf(m, __shfl_xor(m, 2));
                m = fmaxf(m, __shfl_xor(m, 4));
                m = fmaxf(m, __shfl_xor(m, 8));
                float p[4];
                float sum = 0.f;
#pragma unroll
                for (int cb = 0; cb < 4; ++cb) {
                    int c = cb * 16 + c0;
                    p[cb] = (c <= l) ? __expf(vv[cb] - m) : 0.f;
                    sum += p[cb];
                }
                sum += __shfl_xor(sum, 1);
                sum += __shfl_xor(sum, 2);
                sum += __shfl_xor(sum, 4);
                sum += __shfl_xor(sum, 8);
                const float inv = 1.f / sum;
#pragma unroll
                for (int cb = 0; cb < 4; ++cb) {
                    int c = cb * 16 + c0;
                    int byte = (l * 128 + c * 2) ^ ((l & 7) << 4);
                    *(u16*)(Pl + byte) = f2bf(p[cb] * inv);
                }
            }
        }

        asm volatile("s_waitcnt vmcnt(0)" ::: "memory");  // V staging landed

        // PV: attnT[d][l] += sum_c v[c][d] * P[l][c]   (A = v^T scalar reads, B = P rows)
#pragma unroll
        for (int kb = 0; kb < 2; ++kb) {
            bf16x8 pf[4];
#pragma unroll
            for (int lf = 0; lf < 4; ++lf) {
                int l = lf * 16 + (lane & 15);
                int byte = (l * 128 + (kb * 32 + (lane >> 4) * 8) * 2) ^ ((l & 7) << 4);
                pf[lf] = *(const bf16x8*)(Pl + byte);
            }
#pragma unroll
            for (int mf = 0; mf < 4; ++mf) {
                const int d = mf * 16 + (lane & 15);
                const int cb2 = kb * 32 + (lane >> 4) * 8;
                union { bf16x8 v; u16 u[8]; } vt;
#pragma unroll
                for (int e = 0; e < 8; ++e) vt.u[e] = Vl[(cb2 + e) * 64 + d];
#pragma unroll
                for (int lf = 0; lf < 4; ++lf)
                    accT[mf][lf] = __builtin_amdgcn_mfma_f32_16x16x32_bf16(vt.v, pf[lf], accT[mf][lf], 0, 0, 0);
            }
        }
    }

    // block reduce 4 waves -> atomicAdd
    float* red = (float*)smem;
#pragma unroll
    for (int mf = 0; mf < 4; ++mf)
#pragma unroll
        for (int lf = 0; lf < 4; ++lf)
#pragma unroll
            for (int r = 0; r < 4; ++r)
                red[wid * 4096 + (mf * 16 + (lane >> 4) * 4 + r) * 64 + lf * 16 + (lane & 15)] = accT[mf][lf][r];
    __syncthreads();
    for (int idx = tid; idx < 4096; idx += 256) {
        float s = red[idx] + red[4096 + idx] + red[8192 + idx] + red[12288 + idx];
        atomicAdd(&attnT[(size_t)bh * 4096 + idx], s);
    }
}

// ---------------- weighted = softmax(logits*scale) @ attn, store bf16 ----------------
// grid = B*H*32 (t-tiles of 128); block 256 = 4 waves; wave does 32 rows.
__global__ __launch_bounds__(256, 4) void k_weighted(
    const u16* __restrict__ logits, const float* __restrict__ attnT, u16* __restrict__ wout)
{
    const int tid = threadIdx.x, lane = tid & 63, wid = tid >> 6;
    const int bh = blockIdx.x >> 5, tt = blockIdx.x & 31;
    const int b = bh >> 4, h = bh & 15;
    const int t0 = tt * 128 + wid * 32;

    // B-frags: attnT[d][l] f32 -> bf16, B^T[n=d][k=l] contiguous in l
    const float* at = attnT + (size_t)bh * 4096;
    bf16x8 bfr[4][2];
#pragma unroll
    for (int nf = 0; nf < 4; ++nf)
#pragma unroll
        for (int kb = 0; kb < 2; ++kb) {
            const float* src = at + (nf * 16 + (lane & 15)) * 64 + kb * 32 + (lane >> 4) * 8;
            float4 v0 = ((const float4*)src)[0];
            float4 v1 = ((const float4*)src)[1];
            union { bf16x8 v; u16 u[8]; } pk;
            pk.u[0] = f2bf(v0.x); pk.u[1] = f2bf(v0.y); pk.u[2] = f2bf(v0.z); pk.u[3] = f2bf(v0.w);
            pk.u[4] = f2bf(v1.x); pk.u[5] = f2bf(v1.y); pk.u[6] = f2bf(v1.z); pk.u[7] = f2bf(v1.w);
            bfr[nf][kb] = pk.v;
        }

    f32x4 acc[2][4];
#pragma unroll
    for (int i = 0; i < 2; ++i)
#pragma unroll
        for (int j = 0; j < 4; ++j) acc[i][j] = f32x4{0.f, 0.f, 0.f, 0.f};

#pragma unroll
    for (int mf = 0; mf < 2; ++mf) {
        const int t = t0 + mf * 16 + (lane & 15);
        const u16* lrow = logits + ((size_t)b * 4096 + t) * 1024 + h * 64 + (lane >> 4) * 8;
        bf16x8 l0 = *(const bf16x8*)lrow;
        bf16x8 l1 = *(const bf16x8*)(lrow + 32);
        float va[16];
#pragma unroll
        for (int j = 0; j < 8; ++j) {
            va[j] = bf2f((u16)l0[j]) * 0.125f;
            va[8 + j] = bf2f((u16)l1[j]) * 0.125f;
        }
        float m = va[0];
#pragma unroll
        for (int j = 1; j < 16; ++j) m = fmaxf(m, va[j]);
        m = fmaxf(m, __shfl_xor(m, 16));
        m = fmaxf(m, __shfl_xor(m, 32));
        float sum = 0.f;
#pragma unroll
        for (int j = 0; j < 16; ++j) { va[j] = __expf(va[j] - m); sum += va[j]; }
        sum += __shfl_xor(sum, 16);
        sum += __shfl_xor(sum, 32);
        const float inv = 1.f / sum;
        union { bf16x8 v; u16 u[8]; } a0, a1;
#pragma unroll
        for (int j = 0; j < 8; ++j) {
            a0.u[j] = f2bf(va[j] * inv);
            a1.u[j] = f2bf(va[8 + j] * inv);
        }
#pragma unroll
        for (int nf = 0; nf < 4; ++nf) {
            acc[mf][nf] = __builtin_amdgcn_mfma_f32_16x16x32_bf16(a0.v, bfr[nf][0], acc[mf][nf], 0, 0, 0);
            acc[mf][nf] = __builtin_amdgcn_mfma_f32_16x16x32_bf16(a1.v, bfr[nf][1], acc[mf][nf], 0, 0, 0);
        }
    }

#pragma unroll
    for (int mf = 0; mf < 2; ++mf)
#pragma unroll
        for (int nf = 0; nf < 4; ++nf)
#pragma unroll
            for (int r = 0; r < 4; ++r) {
                int t = t0 + mf * 16 + (lane >> 4) * 4 + r;
                wout[((size_t)b * 4096 + t) * 1024 + h * 64 + nf * 16 + (lane & 15)] = f2bf(acc[mf][nf][r]);
            }
}

// ---------------- launch ----------------
extern "C" void kernel_launch(void* const* d_in, const int* in_sizes, int n_in,
                              void* d_out, int out_size, void* d_ws, size_t ws_size,
                              hipStream_t stream)
{
    const float* x  = (const float*)d_in[0];
    const float* lq = (const float*)d_in[1];
    const float* Wk = (const float*)d_in[2];
    const float* Wv = (const float*)d_in[3];
    const float* Wg = (const float*)d_in[4];
    const float* Wp = (const float*)d_in[5];

    char* ws = (char*)d_ws;
    u16*    wkv   = (u16*)(ws + 0);          //  4,194,304  [Wk;Wv] bf16 [2048][1024]
    u16*    wg    = (u16*)(ws + 4194304);    //  2,097,152
    u16*    wp    = (u16*)(ws + 6291456);    //  2,097,152
    float2* rope  = (float2*)(ws + 8388608); //  1,048,576
    float*  attnT = (float*)(ws + 9437184);  //  2,097,152  [B*H][64][64]
    u16*    kv    = (u16*)(ws + 11534336);   // 67,108,864  [16384][2048]; reused as wout
    // d_out (134MB f32): lower half = logits bf16 scratch, upper half = x bf16 scratch
    u16* logits = (u16*)d_out;                       // [32768][1024] bf16
    u16* xb     = (u16*)((char*)d_out + 67108864);   // [32768][1024] bf16

    hipMemsetAsync(attnT, 0, 128 * 4096 * sizeof(float), stream);

    k_cvt<<<2048, 256, 0, stream>>>(x, xb, 33554432 / 4);
    k_cvt<<<512, 256, 0, stream>>>(Wk, wkv, 1048576 / 4);
    k_cvt<<<512, 256, 0, stream>>>(Wv, wkv + 1048576, 1048576 / 4);
    k_cvt<<<512, 256, 0, stream>>>(Wg, wg, 1048576 / 4);
    k_cvt<<<512, 256, 0, stream>>>(Wp, wp, 1048576 / 4);
    k_rope<<<512, 256, 0, stream>>>(rope);

    // KV: M=16384 selected rows, N=2048
    k_gemm<0><<<dim3(16, 128), 256, 0, stream>>>(xb, wkv, kv, rope);
    // gate logits: M=32768, N=1024 (writes lower half of d_out)
    k_gemm<1><<<dim3(8, 256), 256, 0, stream>>>(xb, wg, logits, nullptr);
    // attention -> attnT
    k_attn<<<512, 256, 0, stream>>>(kv, lq, attnT);
    // weighted tokens (overwrites kv region)
    k_weighted<<<4096, 256, 0, stream>>>(logits, attnT, kv);
    // output projection -> d_out f32
    k_gemm<2><<<dim3(8, 256), 256, 0, stream>>>(kv, wp, d_out, nullptr);
}

// Round 4
// 581.311 us; speedup vs baseline: 1.0553x; 1.0553x over previous
//
#include <hip/hip_runtime.h>
#include <hip/hip_bf16.h>

typedef unsigned short u16;
typedef __attribute__((ext_vector_type(8))) short bf16x8;
typedef __attribute__((ext_vector_type(4))) float f32x4;
typedef __attribute__((ext_vector_type(4))) unsigned short u16x4;

#define DEVI static __device__ __forceinline__

DEVI u16 f2bf(float f) {
    union { __hip_bfloat16 h; u16 u; } cv;
    cv.h = __float2bfloat16(f);
    return cv.u;
}
DEVI float bf2f(u16 u) {
    union { u16 u; __hip_bfloat16 h; } cv;
    cv.u = u;
    return __bfloat162float(cv.h);
}

DEVI void gload_lds16(const void* g, void* l) {
    __builtin_amdgcn_global_load_lds(
        (const __attribute__((address_space(1))) unsigned int*)g,
        (__attribute__((address_space(3))) unsigned int*)l, 16, 0, 0);
}

#define BAR asm volatile("s_barrier" ::: "memory")
#define VMW(N) asm volatile("s_waitcnt vmcnt(" #N ")" ::: "memory")

// ---------------- convert f32 -> bf16 (vectorized) ----------------
__global__ void k_cvt(const float* __restrict__ in, u16* __restrict__ out, int n4) {
    int i = blockIdx.x * blockDim.x + threadIdx.x;
    int stride = gridDim.x * blockDim.x;
    for (; i < n4; i += stride) {
        float4 v = ((const float4*)in)[i];
        u16x4 o;
        o.x = f2bf(v.x); o.y = f2bf(v.y); o.z = f2bf(v.z); o.w = f2bf(v.w);
        ((u16x4*)out)[i] = o;
    }
}

// ---------------- rope cos/sin table [4096][32] float2 ----------------
__global__ void k_rope(float2* __restrict__ tab) {
    int i = blockIdx.x * 256 + threadIdx.x;   // 0..131071
    int t = i >> 5, j = i & 31;
    float inv = powf(10000.f, -(float)j / 32.f);
    float ang = (float)t * inv;
    float s, c;
    sincosf(ang, &s, &c);
    tab[i] = make_float2(c, s);
}

// ============ 256x256 8-wave deep-pipelined GEMM, K=1024, BK=64 ============
// C[M,N] = A[M,1024] @ Bw[N,1024]^T
// MODE 0: KV gemm (A rows remapped selected indices; RoPE on cols<1024; bf16 out ld=2048)
// MODE 1: logits gemm (bf16 out ld=1024)
// MODE 2: out gemm (f32 out ld=1024)
// LDS 128 KiB: A[2 buf][2 kh][256 rows][32 k] bf16 at 0; B same at +65536.
// Schedule: 4 phases/K-tile; stage slot s = phase+7 (2 gloads); vmcnt(10) at
// phi1/phi3 AFTER the MFMA cluster (hides wait under compute). Raw s_barrier
// (no vmcnt drain). Verified algebra: every stage >=1 barrier after last read
// of the region it overwrites; vmcnt(10) => next phase-pair operands landed.
template<int MODE>
__global__ __launch_bounds__(512, 2) void k_gemm256(
    const u16* __restrict__ A, const u16* __restrict__ Bw,
    void* __restrict__ Cout, const float2* __restrict__ rope)
{
    extern __shared__ char lds[];
    const int tid = threadIdx.x;
    const int lane = tid & 63, wid = tid >> 6;
    const int wr = wid >> 2, wc = wid & 3;          // 2 x 4 wave grid
    const int koff = (lane >> 4) * 16;              // byte k-offset in 64B row

    // XCD-aware 2D swizzle (bijective; nwg = 512, 8 XCDs, 64 blocks each)
    const int GX = (MODE == 0) ? 8 : 4;
    const int kx = GX >> 1;                          // XCD columns (2 bx each)
    int orig = blockIdx.x + blockIdx.y * GX;
    int xcd = orig & 7, i = orig >> 3;               // i in [0,64)
    int bx = (xcd % kx) * 2 + (i & 1);
    int by = (xcd / kx) * 32 + (i >> 1);
    const int row0 = by * 256, col0 = bx * 256;

    // ---- staging: slot s in [0,64): t=s>>2, which=s&3 {Akh0,Bkh0,Akh1,Bkh1}
    auto stage = [&](int s) {
        const int t = s >> 2;
        const int isB = s & 1;
        const int kh = (s >> 1) & 1;
        char* base = lds + isB * 65536 + (t & 1) * 32768 + kh * 16384;
        const int kbase = t * 64 + kh * 32;          // u16 col in K
#pragma unroll
        for (int j = 0; j < 2; ++j) {
            int idx = j * 512 + tid;                 // chunk: row=idx>>2, kc=idx&3
            int r = idx >> 2;
            int kc = idx & 3;
            int grow;
            if (isB) {
                grow = col0 + r;
            } else {
                grow = row0 + r;
                if (MODE == 0)
                    grow = ((grow >> 11) << 12) | (((grow >> 6) & 31) << 7) | (grow & 63);
            }
            const u16* g = (isB ? Bw : A) + (size_t)grow * 1024 + kbase + kc * 8;
            // lane-uniform LDS base; HW adds lane*16
            gload_lds16(g, base + j * 8192 + wid * 1024);
        }
    };

    bf16x8 af[8];
    bf16x8 bq[2];
    f32x4 acc[8][4];
#pragma unroll
    for (int m = 0; m < 8; ++m)
#pragma unroll
        for (int n = 0; n < 4; ++n) acc[m][n] = f32x4{0.f, 0.f, 0.f, 0.f};

#define LDA(T, KH) do { \
    const char* ab_ = lds + ((T) & 1) * 32768 + (KH) * 16384; \
    _Pragma("unroll") \
    for (int mf = 0; mf < 8; ++mf) \
        af[mf] = *(const bf16x8*)(ab_ + (wr * 128 + mf * 16 + (lane & 15)) * 64 + koff); \
} while (0)

#define LDB(T, KH, NH) do { \
    const char* bb_ = lds + 65536 + ((T) & 1) * 32768 + (KH) * 16384; \
    bq[0] = *(const bf16x8*)(bb_ + (wc * 64 + ((NH) * 2)     * 16 + (lane & 15)) * 64 + koff); \
    bq[1] = *(const bf16x8*)(bb_ + (wc * 64 + ((NH) * 2 + 1) * 16 + (lane & 15)) * 64 + koff); \
} while (0)

#define MMA(NH) do { \
    __builtin_amdgcn_s_setprio(1); \
    _Pragma("unroll") \
    for (int mf = 0; mf < 8; ++mf) { \
        acc[mf][2 * (NH)]     = __builtin_amdgcn_mfma_f32_16x16x32_bf16(af[mf], bq[0], acc[mf][2 * (NH)], 0, 0, 0); \
        acc[mf][2 * (NH) + 1] = __builtin_amdgcn_mfma_f32_16x16x32_bf16(af[mf], bq[1], acc[mf][2 * (NH) + 1], 0, 0, 0); \
    } \
    __builtin_amdgcn_s_setprio(0); \
} while (0)

    // prologue: slots 0..6 (14 loads); wait until slots 0,1 landed (keep 10 newest)
#pragma unroll 1
    for (int s = 0; s < 7; ++s) stage(s);
    VMW(10);
    BAR;

    // steady tiles 0..13
#pragma unroll 1
    for (int t = 0; t < 14; ++t) {
        // phi0: reads kh0 (A + B nf0,1); stages slot 4t+7 (tile t+1 B kh1)
        LDA(t, 0); LDB(t, 0, 0);
        stage(4 * t + 7);
        BAR; MMA(0); BAR;
        // phi1: B kh0 nf2,3; stage 4t+8 (t+2 A kh0); vmcnt -> tile t kh1 landed
        LDB(t, 0, 1);
        stage(4 * t + 8);
        BAR; MMA(1); VMW(10); BAR;
        // phi2: kh1 (A + B nf0,1); stage 4t+9 (t+2 B kh0)
        LDA(t, 1); LDB(t, 1, 0);
        stage(4 * t + 9);
        BAR; MMA(0); BAR;
        // phi3: B kh1 nf2,3; stage 4t+10 (t+2 A kh1); vmcnt -> tile t+1 kh0 landed
        LDB(t, 1, 1);
        stage(4 * t + 10);
        BAR; MMA(1); VMW(10); BAR;
    }
    // tile 14 (stage only slot 63; vmcnt 8 then 4)
    LDA(14, 0); LDB(14, 0, 0); stage(63); BAR; MMA(0); BAR;
    LDB(14, 0, 1);                         BAR; MMA(1); VMW(8); BAR;
    LDA(14, 1); LDB(14, 1, 0);             BAR; MMA(0); BAR;
    LDB(14, 1, 1);                         BAR; MMA(1); VMW(4); BAR;
    // tile 15 (no stages; drain before kh1)
    LDA(15, 0); LDB(15, 0, 0);             BAR; MMA(0); BAR;
    LDB(15, 0, 1);                         BAR; MMA(1); VMW(0); BAR;
    LDA(15, 1); LDB(15, 1, 0);             BAR; MMA(0); BAR;
    LDB(15, 1, 1);                         BAR; MMA(1);

#undef LDA
#undef LDB
#undef MMA

    // ---- epilogue: C/D layout col=lane&15, row=(lane>>4)*4+r
    const int rbase = row0 + wr * 128 + ((lane >> 4) << 2);
    const int cbase = col0 + wc * 64 + (lane & 15);
#pragma unroll
    for (int mf = 0; mf < 8; ++mf) {
#pragma unroll
        for (int nf = 0; nf < 4; ++nf) {
            const int gc = cbase + nf * 16;
#pragma unroll
            for (int r = 0; r < 4; ++r) {
                const int gr = rbase + mf * 16 + r;
                float v = acc[mf][nf][r];
                if (MODE == 0) {
                    float o = __shfl_xor(v, 1);
                    float res;
                    if (gc < 1024) {  // K half gets RoPE (uniform per block)
                        int t = (((gr >> 6) & 31) << 7) | (gr & 63);
                        float2 cs = rope[t * 32 + ((gc & 63) >> 1)];
                        res = (gc & 1) ? (o * cs.y + v * cs.x) : (v * cs.x - o * cs.y);
                    } else {
                        res = v;
                    }
                    ((u16*)Cout)[(size_t)gr * 2048 + gc] = f2bf(res);
                } else if (MODE == 1) {
                    ((u16*)Cout)[(size_t)gr * 1024 + gc] = f2bf(v);
                } else {
                    ((float*)Cout)[(size_t)gr * 1024 + gc] = v;
                }
            }
        }
    }
}

// ---------------- attention: per (b,h) accumulate attnT[d][l] ----------------
__global__ __launch_bounds__(256, 2) void k_attn(
    const u16* __restrict__ kv, const float* __restrict__ lq, float* __restrict__ attnT)
{
    __shared__ char smem[65536];
    const int tid = threadIdx.x;
    const int lane = tid & 63, wid = tid >> 6;
    const int gidx = blockIdx.x & 3;
    const int bh = blockIdx.x >> 2;
    const int b = bh >> 4, h = bh & 15;

    bf16x8 qf[4][2];
#pragma unroll
    for (int lb = 0; lb < 4; ++lb)
#pragma unroll
        for (int kb = 0; kb < 2; ++kb) {
            const float* src = lq + ((size_t)(lb * 16 + (lane & 15)) * 16 + h) * 64 + kb * 32 + (lane >> 4) * 8;
            float4 v0 = ((const float4*)src)[0];
            float4 v1 = ((const float4*)src)[1];
            union { bf16x8 v; u16 u[8]; } pk;
            pk.u[0] = f2bf(v0.x * 0.125f); pk.u[1] = f2bf(v0.y * 0.125f);
            pk.u[2] = f2bf(v0.z * 0.125f); pk.u[3] = f2bf(v0.w * 0.125f);
            pk.u[4] = f2bf(v1.x * 0.125f); pk.u[5] = f2bf(v1.y * 0.125f);
            pk.u[6] = f2bf(v1.z * 0.125f); pk.u[7] = f2bf(v1.w * 0.125f);
            qf[lb][kb] = pk.v;
        }

    char* Pl = smem + wid * 16384;
    char* Vb = smem + wid * 16384 + 8192;
    u16* Vl = (u16*)Vb;

    f32x4 accT[4][4];
#pragma unroll
    for (int i = 0; i < 4; ++i)
#pragma unroll
        for (int j = 0; j < 4; ++j) accT[i][j] = f32x4{0.f, 0.f, 0.f, 0.f};

#pragma unroll 1
    for (int ci = 0; ci < 2; ++ci) {
        const int n = gidx * 8 + wid * 2 + ci;
        const size_t krow = (size_t)b * 2048 + (size_t)n * 64;

#pragma unroll
        for (int j = 0; j < 8; ++j) {
            const u16* g = kv + (krow + j * 8 + (lane >> 3)) * 2048 + 1024 + h * 64 + (lane & 7) * 8;
            gload_lds16(g, Vb + j * 1024);
        }

        f32x4 S[4][4];
#pragma unroll
        for (int i = 0; i < 4; ++i)
#pragma unroll
            for (int j = 0; j < 4; ++j) S[i][j] = f32x4{0.f, 0.f, 0.f, 0.f};
#pragma unroll
        for (int kb = 0; kb < 2; ++kb) {
            bf16x8 kf[4];
#pragma unroll
            for (int cb = 0; cb < 4; ++cb)
                kf[cb] = *(const bf16x8*)(kv + (krow + cb * 16 + (lane & 15)) * 2048 + h * 64 + kb * 32 + (lane >> 4) * 8);
#pragma unroll
            for (int lb = 0; lb < 4; ++lb)
#pragma unroll
                for (int cb = 0; cb < 4; ++cb)
                    S[lb][cb] = __builtin_amdgcn_mfma_f32_16x16x32_bf16(qf[lb][kb], kf[cb], S[lb][cb], 0, 0, 0);
        }

#pragma unroll
        for (int lb = 0; lb < 4; ++lb) {
#pragma unroll
            for (int r = 0; r < 4; ++r) {
                const int l = lb * 16 + (lane >> 4) * 4 + r;
                const int c0 = lane & 15;
                float vv[4];
                float m = -3e30f;
#pragma unroll
                for (int cb = 0; cb < 4; ++cb) {
                    int c = cb * 16 + c0;
                    vv[cb] = (c <= l) ? S[lb][cb][r] : -3e30f;
                    m = fmaxf(m, vv[cb]);
                }
                m = fmaxf(m, __shfl_xor(m, 1));
                m = fmaxf(m, __shfl_xor(m, 2));
                m = fmaxf(m, __shfl_xor(m, 4));
                m = fmaxf(m, __shfl_xor(m, 8));
                float p[4];
                float sum = 0.f;
#pragma unroll
                for (int cb = 0; cb < 4; ++cb) {
                    int c = cb * 16 + c0;
                    p[cb] = (c <= l) ? __expf(vv[cb] - m) : 0.f;
                    sum += p[cb];
                }
                sum += __shfl_xor(sum, 1);
                sum += __shfl_xor(sum, 2);
                sum += __shfl_xor(sum, 4);
                sum += __shfl_xor(sum, 8);
                const float inv = 1.f / sum;
#pragma unroll
                for (int cb = 0; cb < 4; ++cb) {
                    int c = cb * 16 + c0;
                    int byte = (l * 128 + c * 2) ^ ((l & 7) << 4);
                    *(u16*)(Pl + byte) = f2bf(p[cb] * inv);
                }
            }
        }

        asm volatile("s_waitcnt vmcnt(0)" ::: "memory");

#pragma unroll
        for (int kb = 0; kb < 2; ++kb) {
            bf16x8 pf[4];
#pragma unroll
            for (int lf = 0; lf < 4; ++lf) {
                int l = lf * 16 + (lane & 15);
                int byte = (l * 128 + (kb * 32 + (lane >> 4) * 8) * 2) ^ ((l & 7) << 4);
                pf[lf] = *(const bf16x8*)(Pl + byte);
            }
#pragma unroll
            for (int mf = 0; mf < 4; ++mf) {
                const int d = mf * 16 + (lane & 15);
                const int cb2 = kb * 32 + (lane >> 4) * 8;
                union { bf16x8 v; u16 u[8]; } vt;
#pragma unroll
                for (int e = 0; e < 8; ++e) vt.u[e] = Vl[(cb2 + e) * 64 + d];
#pragma unroll
                for (int lf = 0; lf < 4; ++lf)
                    accT[mf][lf] = __builtin_amdgcn_mfma_f32_16x16x32_bf16(vt.v, pf[lf], accT[mf][lf], 0, 0, 0);
            }
        }
    }

    float* red = (float*)smem;
#pragma unroll
    for (int mf = 0; mf < 4; ++mf)
#pragma unroll
        for (int lf = 0; lf < 4; ++lf)
#pragma unroll
            for (int r = 0; r < 4; ++r)
                red[wid * 4096 + (mf * 16 + (lane >> 4) * 4 + r) * 64 + lf * 16 + (lane & 15)] = accT[mf][lf][r];
    __syncthreads();
    for (int idx = tid; idx < 4096; idx += 256) {
        float s = red[idx] + red[4096 + idx] + red[8192 + idx] + red[12288 + idx];
        atomicAdd(&attnT[(size_t)bh * 4096 + idx], s);
    }
}

// ---------------- weighted = softmax(logits*scale) @ attn, store bf16 ----------------
__global__ __launch_bounds__(256, 4) void k_weighted(
    const u16* __restrict__ logits, const float* __restrict__ attnT, u16* __restrict__ wout)
{
    const int tid = threadIdx.x, lane = tid & 63, wid = tid >> 6;
    const int bh = blockIdx.x >> 5, tt = blockIdx.x & 31;
    const int b = bh >> 4, h = bh & 15;
    const int t0 = tt * 128 + wid * 32;

    const float* at = attnT + (size_t)bh * 4096;
    bf16x8 bfr[4][2];
#pragma unroll
    for (int nf = 0; nf < 4; ++nf)
#pragma unroll
        for (int kb = 0; kb < 2; ++kb) {
            const float* src = at + (nf * 16 + (lane & 15)) * 64 + kb * 32 + (lane >> 4) * 8;
            float4 v0 = ((const float4*)src)[0];
            float4 v1 = ((const float4*)src)[1];
            union { bf16x8 v; u16 u[8]; } pk;
            pk.u[0] = f2bf(v0.x); pk.u[1] = f2bf(v0.y); pk.u[2] = f2bf(v0.z); pk.u[3] = f2bf(v0.w);
            pk.u[4] = f2bf(v1.x); pk.u[5] = f2bf(v1.y); pk.u[6] = f2bf(v1.z); pk.u[7] = f2bf(v1.w);
            bfr[nf][kb] = pk.v;
        }

    f32x4 acc[2][4];
#pragma unroll
    for (int i = 0; i < 2; ++i)
#pragma unroll
        for (int j = 0; j < 4; ++j) acc[i][j] = f32x4{0.f, 0.f, 0.f, 0.f};

#pragma unroll
    for (int mf = 0; mf < 2; ++mf) {
        const int t = t0 + mf * 16 + (lane & 15);
        const u16* lrow = logits + ((size_t)b * 4096 + t) * 1024 + h * 64 + (lane >> 4) * 8;
        bf16x8 l0 = *(const bf16x8*)lrow;
        bf16x8 l1 = *(const bf16x8*)(lrow + 32);
        float va[16];
#pragma unroll
        for (int j = 0; j < 8; ++j) {
            va[j] = bf2f((u16)l0[j]) * 0.125f;
            va[8 + j] = bf2f((u16)l1[j]) * 0.125f;
        }
        float m = va[0];
#pragma unroll
        for (int j = 1; j < 16; ++j) m = fmaxf(m, va[j]);
        m = fmaxf(m, __shfl_xor(m, 16));
        m = fmaxf(m, __shfl_xor(m, 32));
        float sum = 0.f;
#pragma unroll
        for (int j = 0; j < 16; ++j) { va[j] = __expf(va[j] - m); sum += va[j]; }
        sum += __shfl_xor(sum, 16);
        sum += __shfl_xor(sum, 32);
        const float inv = 1.f / sum;
        union { bf16x8 v; u16 u[8]; } a0, a1;
#pragma unroll
        for (int j = 0; j < 8; ++j) {
            a0.u[j] = f2bf(va[j] * inv);
            a1.u[j] = f2bf(va[8 + j] * inv);
        }
#pragma unroll
        for (int nf = 0; nf < 4; ++nf) {
            acc[mf][nf] = __builtin_amdgcn_mfma_f32_16x16x32_bf16(a0.v, bfr[nf][0], acc[mf][nf], 0, 0, 0);
            acc[mf][nf] = __builtin_amdgcn_mfma_f32_16x16x32_bf16(a1.v, bfr[nf][1], acc[mf][nf], 0, 0, 0);
        }
    }

#pragma unroll
    for (int mf = 0; mf < 2; ++mf)
#pragma unroll
        for (int nf = 0; nf < 4; ++nf)
#pragma unroll
            for (int r = 0; r < 4; ++r) {
                int t = t0 + mf * 16 + (lane >> 4) * 4 + r;
                wout[((size_t)b * 4096 + t) * 1024 + h * 64 + nf * 16 + (lane & 15)] = f2bf(acc[mf][nf][r]);
            }
}

// ---------------- launch ----------------
extern "C" void kernel_launch(void* const* d_in, const int* in_sizes, int n_in,
                              void* d_out, int out_size, void* d_ws, size_t ws_size,
                              hipStream_t stream)
{
    const float* x  = (const float*)d_in[0];
    const float* lq = (const float*)d_in[1];
    const float* Wk = (const float*)d_in[2];
    const float* Wv = (const float*)d_in[3];
    const float* Wg = (const float*)d_in[4];
    const float* Wp = (const float*)d_in[5];

    char* ws = (char*)d_ws;
    u16*    wkv   = (u16*)(ws + 0);          //  4,194,304  [Wk;Wv] bf16 [2048][1024]
    u16*    wg    = (u16*)(ws + 4194304);    //  2,097,152
    u16*    wp    = (u16*)(ws + 6291456);    //  2,097,152
    float2* rope  = (float2*)(ws + 8388608); //  1,048,576
    float*  attnT = (float*)(ws + 9437184);  //  2,097,152  [B*H][64][64]
    u16*    kv    = (u16*)(ws + 11534336);   // 67,108,864  [16384][2048]; reused as wout
    u16* logits = (u16*)d_out;                       // [32768][1024] bf16
    u16* xb     = (u16*)((char*)d_out + 67108864);   // [32768][1024] bf16

    hipFuncSetAttribute((const void*)k_gemm256<0>, hipFuncAttributeMaxDynamicSharedMemorySize, 131072);
    hipFuncSetAttribute((const void*)k_gemm256<1>, hipFuncAttributeMaxDynamicSharedMemorySize, 131072);
    hipFuncSetAttribute((const void*)k_gemm256<2>, hipFuncAttributeMaxDynamicSharedMemorySize, 131072);

    hipMemsetAsync(attnT, 0, 128 * 4096 * sizeof(float), stream);

    k_cvt<<<2048, 256, 0, stream>>>(x, xb, 33554432 / 4);
    k_cvt<<<512, 256, 0, stream>>>(Wk, wkv, 1048576 / 4);
    k_cvt<<<512, 256, 0, stream>>>(Wv, wkv + 1048576, 1048576 / 4);
    k_cvt<<<512, 256, 0, stream>>>(Wg, wg, 1048576 / 4);
    k_cvt<<<512, 256, 0, stream>>>(Wp, wp, 1048576 / 4);
    k_rope<<<512, 256, 0, stream>>>(rope);

    // KV: M=16384 selected rows, N=2048
    k_gemm256<0><<<dim3(8, 64), 512, 131072, stream>>>(xb, wkv, kv, rope);
    // gate logits: M=32768, N=1024
    k_gemm256<1><<<dim3(4, 128), 512, 131072, stream>>>(xb, wg, logits, nullptr);
    // attention -> attnT
    k_attn<<<512, 256, 0, stream>>>(kv, lq, attnT);
    // weighted tokens (overwrites kv region)
    k_weighted<<<4096, 256, 0, stream>>>(logits, attnT, kv);
    // output projection -> d_out f32
    k_gemm256<2><<<dim3(4, 128), 512, 131072, stream>>>(kv, wp, d_out, nullptr);
}

// Round 5
// 573.440 us; speedup vs baseline: 1.0698x; 1.0137x over previous
//
#include <hip/hip_runtime.h>
#include <hip/hip_bf16.h>

typedef unsigned short u16;
typedef __attribute__((ext_vector_type(8))) short bf16x8;
typedef __attribute__((ext_vector_type(4))) float f32x4;
typedef __attribute__((ext_vector_type(4))) unsigned short u16x4;

#define DEVI static __device__ __forceinline__

DEVI u16 f2bf(float f) {
    union { __hip_bfloat16 h; u16 u; } cv;
    cv.h = __float2bfloat16(f);
    return cv.u;
}
DEVI float bf2f(u16 u) {
    union { u16 u; __hip_bfloat16 h; } cv;
    cv.u = u;
    return __bfloat162float(cv.h);
}

DEVI void gload_lds16(const void* g, void* l) {
    __builtin_amdgcn_global_load_lds(
        (const __attribute__((address_space(1))) unsigned int*)g,
        (__attribute__((address_space(3))) unsigned int*)l, 16, 0, 0);
}

#define BAR asm volatile("s_barrier" ::: "memory")
#define VMW(N) asm volatile("s_waitcnt vmcnt(" #N ")" ::: "memory")

// ---------------- convert f32 -> bf16 (vectorized) ----------------
__global__ void k_cvt(const float* __restrict__ in, u16* __restrict__ out, int n4) {
    int i = blockIdx.x * blockDim.x + threadIdx.x;
    int stride = gridDim.x * blockDim.x;
    for (; i < n4; i += stride) {
        float4 v = ((const float4*)in)[i];
        u16x4 o;
        o.x = f2bf(v.x); o.y = f2bf(v.y); o.z = f2bf(v.z); o.w = f2bf(v.w);
        ((u16x4*)out)[i] = o;
    }
}

// ---------------- rope cos/sin table [4096][32] float2 ----------------
__global__ void k_rope(float2* __restrict__ tab) {
    int i = blockIdx.x * 256 + threadIdx.x;   // 0..131071
    int t = i >> 5, j = i & 31;
    float inv = powf(10000.f, -(float)j / 32.f);
    float ang = (float)t * inv;
    float s, c;
    sincosf(ang, &s, &c);
    tab[i] = make_float2(c, s);
}

// ============ 256x256 8-wave deep-pipelined GEMM, K=1024, BK=64 ============
// C[M,N] = A[M,1024] @ Bw[N,1024]^T
// MODE 0: KV gemm (A rows remapped selected indices; RoPE on cols<1024; bf16 out ld=2048)
// MODE 1: logits gemm (bf16 out ld=1024)   MODE 2: out gemm (f32 out ld=1024)
//
// LDS 128 KiB: A[2buf][2kh][256r][32k u16] at 0; B same at +65536. 64B rows.
// BANK SWIZZLE (T2 under the global_load_lds linear-dest constraint):
//   physical k-byte = logical ^ (((row>>1)&3)<<4). Write side: permute the
//   per-lane GLOBAL k (k_u16 ^= ((tid>>3)&3)*8); read side: kswz constant.
//   Quarter-wave (16 rows @64B stride) goes 8-way -> 2-way (free, m136).
// SCHEDULE: 2 phases/tile {12 ds_read; 2 stage slots; BAR; 32 MFMA; VMW(8); BAR}
//   slots: s=4t+{0,1,2,3} = {Akh0,Bkh0,Akh1,Bkh1}; phi0 stages {4t+6,4t+7},
//   phi1 stages {4t+8,4t+9}. Every staged region is >=1 barrier past its last
//   reader; VMW(8) at phase close guarantees next phase's 2 slots landed.
template<int MODE>
__global__ __launch_bounds__(512, 2) void k_gemm256(
    const u16* __restrict__ A, const u16* __restrict__ Bw,
    void* __restrict__ Cout, const float2* __restrict__ rope)
{
    extern __shared__ char lds[];
    const int tid = threadIdx.x;
    const int lane = tid & 63, wid = tid >> 6;
    const int wr = wid >> 2, wc = wid & 3;          // 2 x 4 wave grid
    // read-side swizzled k-offset (bytes within 64B row); same for A and B
    const int kswz = (((lane >> 4) ^ ((lane >> 1) & 3)) << 4);

    // XCD-aware 2D swizzle (bijective; nwg = 512, 8 XCDs, 64 blocks each)
    const int GX = (MODE == 0) ? 8 : 4;
    const int kx = GX >> 1;
    int orig = blockIdx.x + blockIdx.y * GX;
    int xcd = orig & 7, i = orig >> 3;
    int bx = (xcd % kx) * 2 + (i & 1);
    int by = (xcd / kx) * 32 + (i >> 1);
    const int row0 = by * 256, col0 = bx * 256;

    // ---- staging: slot s in [0,64): t=s>>2, isB=s&1, kh=(s>>1)&1 (16KB each)
    auto stage = [&](int s) {
        const int t = s >> 2;
        const int isB = s & 1;
        const int kh = (s >> 1) & 1;
        char* base = lds + isB * 65536 + (t & 1) * 32768 + kh * 16384;
        const int kbase = t * 64 + kh * 32;          // u16 col in K
#pragma unroll
        for (int j = 0; j < 2; ++j) {
            int idx = j * 512 + tid;                 // phys: row=idx>>2, kc=idx&3
            int r = idx >> 2;
            int kc = idx & 3;
            int grow;
            if (isB) {
                grow = col0 + r;
            } else {
                grow = row0 + r;
                if (MODE == 0)
                    grow = ((grow >> 11) << 12) | (((grow >> 6) & 31) << 7) | (grow & 63);
            }
            // inverse-swizzle on the GLOBAL source k (rule #21)
            const u16* g = (isB ? Bw : A) + (size_t)grow * 1024 + kbase
                         + ((kc ^ ((idx >> 3) & 3)) * 8);
            gload_lds16(g, base + j * 8192 + wid * 1024);
        }
    };

    bf16x8 af[8];
    bf16x8 bq[4];
    f32x4 acc[8][4];
#pragma unroll
    for (int m = 0; m < 8; ++m)
#pragma unroll
        for (int n = 0; n < 4; ++n) acc[m][n] = f32x4{0.f, 0.f, 0.f, 0.f};

#define LDA(T, KH) do { \
    const char* ab_ = lds + ((T) & 1) * 32768 + (KH) * 16384; \
    _Pragma("unroll") \
    for (int mf = 0; mf < 8; ++mf) \
        af[mf] = *(const bf16x8*)(ab_ + (wr * 128 + mf * 16 + (lane & 15)) * 64 + kswz); \
} while (0)

#define LDB(T, KH) do { \
    const char* bb_ = lds + 65536 + ((T) & 1) * 32768 + (KH) * 16384; \
    _Pragma("unroll") \
    for (int nf = 0; nf < 4; ++nf) \
        bq[nf] = *(const bf16x8*)(bb_ + (wc * 64 + nf * 16 + (lane & 15)) * 64 + kswz); \
} while (0)

#define MMAALL do { \
    __builtin_amdgcn_s_setprio(1); \
    _Pragma("unroll") \
    for (int mf = 0; mf < 8; ++mf) \
        _Pragma("unroll") \
        for (int nf = 0; nf < 4; ++nf) \
            acc[mf][nf] = __builtin_amdgcn_mfma_f32_16x16x32_bf16(af[mf], bq[nf], acc[mf][nf], 0, 0, 0); \
    __builtin_amdgcn_s_setprio(0); \
} while (0)

    // prologue: slots 0..5 (12 gloads); wait slots 0,1 landed
#pragma unroll 1
    for (int s = 0; s < 6; ++s) stage(s);
    VMW(8);
    BAR;

    // steady tiles 0..13
#pragma unroll 1
    for (int t = 0; t < 14; ++t) {
        // phi0 (kh0): stage tile t+1 kh1 halves (opposite buffer)
        LDA(t, 0); LDB(t, 0);
        stage(4 * t + 6); stage(4 * t + 7);
        BAR; MMAALL; VMW(8); BAR;
        // phi1 (kh1): stage tile t+2 kh0 halves (this buffer, read in phi0)
        LDA(t, 1); LDB(t, 1);
        stage(4 * t + 8); stage(4 * t + 9);
        BAR; MMAALL; VMW(8); BAR;
    }
    // tile 14: phi0 stages {62,63}; phi1 stages none
    LDA(14, 0); LDB(14, 0); stage(62); stage(63); BAR; MMAALL; VMW(8); BAR;
    LDA(14, 1); LDB(14, 1);                        BAR; MMAALL; VMW(4); BAR;
    // tile 15: no stages
    LDA(15, 0); LDB(15, 0);                        BAR; MMAALL; VMW(0); BAR;
    LDA(15, 1); LDB(15, 1);                        BAR; MMAALL;

#undef LDA
#undef LDB
#undef MMAALL

    // ---- epilogue: C/D layout col=lane&15, row=(lane>>4)*4+r
    const int rbase = row0 + wr * 128 + ((lane >> 4) << 2);
    const int cbase = col0 + wc * 64 + (lane & 15);
#pragma unroll
    for (int mf = 0; mf < 8; ++mf) {
#pragma unroll
        for (int nf = 0; nf < 4; ++nf) {
            const int gc = cbase + nf * 16;
#pragma unroll
            for (int r = 0; r < 4; ++r) {
                const int gr = rbase + mf * 16 + r;
                float v = acc[mf][nf][r];
                if (MODE == 0) {
                    float o = __shfl_xor(v, 1);
                    float res;
                    if (gc < 1024) {  // K half gets RoPE (uniform per block)
                        int t = (((gr >> 6) & 31) << 7) | (gr & 63);
                        float2 cs = rope[t * 32 + ((gc & 63) >> 1)];
                        res = (gc & 1) ? (o * cs.y + v * cs.x) : (v * cs.x - o * cs.y);
                    } else {
                        res = v;
                    }
                    ((u16*)Cout)[(size_t)gr * 2048 + gc] = f2bf(res);
                } else if (MODE == 1) {
                    ((u16*)Cout)[(size_t)gr * 1024 + gc] = f2bf(v);
                } else {
                    ((float*)Cout)[(size_t)gr * 1024 + gc] = v;
                }
            }
        }
    }
}

// ---------------- attention: per (b,h) accumulate attnT[d][l] ----------------
__global__ __launch_bounds__(256, 2) void k_attn(
    const u16* __restrict__ kv, const float* __restrict__ lq, float* __restrict__ attnT)
{
    __shared__ char smem[65536];
    const int tid = threadIdx.x;
    const int lane = tid & 63, wid = tid >> 6;
    const int gidx = blockIdx.x & 3;
    const int bh = blockIdx.x >> 2;
    const int b = bh >> 4, h = bh & 15;

    bf16x8 qf[4][2];
#pragma unroll
    for (int lb = 0; lb < 4; ++lb)
#pragma unroll
        for (int kb = 0; kb < 2; ++kb) {
            const float* src = lq + ((size_t)(lb * 16 + (lane & 15)) * 16 + h) * 64 + kb * 32 + (lane >> 4) * 8;
            float4 v0 = ((const float4*)src)[0];
            float4 v1 = ((const float4*)src)[1];
            union { bf16x8 v; u16 u[8]; } pk;
            pk.u[0] = f2bf(v0.x * 0.125f); pk.u[1] = f2bf(v0.y * 0.125f);
            pk.u[2] = f2bf(v0.z * 0.125f); pk.u[3] = f2bf(v0.w * 0.125f);
            pk.u[4] = f2bf(v1.x * 0.125f); pk.u[5] = f2bf(v1.y * 0.125f);
            pk.u[6] = f2bf(v1.z * 0.125f); pk.u[7] = f2bf(v1.w * 0.125f);
            qf[lb][kb] = pk.v;
        }

    char* Pl = smem + wid * 16384;
    char* Vb = smem + wid * 16384 + 8192;
    u16* Vl = (u16*)Vb;

    f32x4 accT[4][4];
#pragma unroll
    for (int i = 0; i < 4; ++i)
#pragma unroll
        for (int j = 0; j < 4; ++j) accT[i][j] = f32x4{0.f, 0.f, 0.f, 0.f};

#pragma unroll 1
    for (int ci = 0; ci < 2; ++ci) {
        const int n = gidx * 8 + wid * 2 + ci;
        const size_t krow = (size_t)b * 2048 + (size_t)n * 64;

#pragma unroll
        for (int j = 0; j < 8; ++j) {
            const u16* g = kv + (krow + j * 8 + (lane >> 3)) * 2048 + 1024 + h * 64 + (lane & 7) * 8;
            gload_lds16(g, Vb + j * 1024);
        }

        f32x4 S[4][4];
#pragma unroll
        for (int i = 0; i < 4; ++i)
#pragma unroll
            for (int j = 0; j < 4; ++j) S[i][j] = f32x4{0.f, 0.f, 0.f, 0.f};
#pragma unroll
        for (int kb = 0; kb < 2; ++kb) {
            bf16x8 kf[4];
#pragma unroll
            for (int cb = 0; cb < 4; ++cb)
                kf[cb] = *(const bf16x8*)(kv + (krow + cb * 16 + (lane & 15)) * 2048 + h * 64 + kb * 32 + (lane >> 4) * 8);
#pragma unroll
            for (int lb = 0; lb < 4; ++lb)
#pragma unroll
                for (int cb = 0; cb < 4; ++cb)
                    S[lb][cb] = __builtin_amdgcn_mfma_f32_16x16x32_bf16(qf[lb][kb], kf[cb], S[lb][cb], 0, 0, 0);
        }

#pragma unroll
        for (int lb = 0; lb < 4; ++lb) {
#pragma unroll
            for (int r = 0; r < 4; ++r) {
                const int l = lb * 16 + (lane >> 4) * 4 + r;
                const int c0 = lane & 15;
                float vv[4];
                float m = -3e30f;
#pragma unroll
                for (int cb = 0; cb < 4; ++cb) {
                    int c = cb * 16 + c0;
                    vv[cb] = (c <= l) ? S[lb][cb][r] : -3e30f;
                    m = fmaxf(m, vv[cb]);
                }
                m = fmaxf(m, __shfl_xor(m, 1));
                m = fmaxf(m, __shfl_xor(m, 2));
                m = fmaxf(m, __shfl_xor(m, 4));
                m = fmaxf(m, __shfl_xor(m, 8));
                float p[4];
                float sum = 0.f;
#pragma unroll
                for (int cb = 0; cb < 4; ++cb) {
                    int c = cb * 16 + c0;
                    p[cb] = (c <= l) ? __expf(vv[cb] - m) : 0.f;
                    sum += p[cb];
                }
                sum += __shfl_xor(sum, 1);
                sum += __shfl_xor(sum, 2);
                sum += __shfl_xor(sum, 4);
                sum += __shfl_xor(sum, 8);
                const float inv = 1.f / sum;
#pragma unroll
                for (int cb = 0; cb < 4; ++cb) {
                    int c = cb * 16 + c0;
                    int byte = (l * 128 + c * 2) ^ ((l & 7) << 4);
                    *(u16*)(Pl + byte) = f2bf(p[cb] * inv);
                }
            }
        }

        asm volatile("s_waitcnt vmcnt(0)" ::: "memory");

#pragma unroll
        for (int kb = 0; kb < 2; ++kb) {
            bf16x8 pf[4];
#pragma unroll
            for (int lf = 0; lf < 4; ++lf) {
                int l = lf * 16 + (lane & 15);
                int byte = (l * 128 + (kb * 32 + (lane >> 4) * 8) * 2) ^ ((l & 7) << 4);
                pf[lf] = *(const bf16x8*)(Pl + byte);
            }
#pragma unroll
            for (int mf = 0; mf < 4; ++mf) {
                const int d = mf * 16 + (lane & 15);
                const int cb2 = kb * 32 + (lane >> 4) * 8;
                union { bf16x8 v; u16 u[8]; } vt;
#pragma unroll
                for (int e = 0; e < 8; ++e) vt.u[e] = Vl[(cb2 + e) * 64 + d];
#pragma unroll
                for (int lf = 0; lf < 4; ++lf)
                    accT[mf][lf] = __builtin_amdgcn_mfma_f32_16x16x32_bf16(vt.v, pf[lf], accT[mf][lf], 0, 0, 0);
            }
        }
    }

    float* red = (float*)smem;
#pragma unroll
    for (int mf = 0; mf < 4; ++mf)
#pragma unroll
        for (int lf = 0; lf < 4; ++lf)
#pragma unroll
            for (int r = 0; r < 4; ++r)
                red[wid * 4096 + (mf * 16 + (lane >> 4) * 4 + r) * 64 + lf * 16 + (lane & 15)] = accT[mf][lf][r];
    __syncthreads();
    for (int idx = tid; idx < 4096; idx += 256) {
        float s = red[idx] + red[4096 + idx] + red[8192 + idx] + red[12288 + idx];
        atomicAdd(&attnT[(size_t)bh * 4096 + idx], s);
    }
}

// ---------------- weighted = softmax(logits*scale) @ attn, store bf16 ----------------
__global__ __launch_bounds__(256, 4) void k_weighted(
    const u16* __restrict__ logits, const float* __restrict__ attnT, u16* __restrict__ wout)
{
    const int tid = threadIdx.x, lane = tid & 63, wid = tid >> 6;
    const int bh = blockIdx.x >> 5, tt = blockIdx.x & 31;
    const int b = bh >> 4, h = bh & 15;
    const int t0 = tt * 128 + wid * 32;

    const float* at = attnT + (size_t)bh * 4096;
    bf16x8 bfr[4][2];
#pragma unroll
    for (int nf = 0; nf < 4; ++nf)
#pragma unroll
        for (int kb = 0; kb < 2; ++kb) {
            const float* src = at + (nf * 16 + (lane & 15)) * 64 + kb * 32 + (lane >> 4) * 8;
            float4 v0 = ((const float4*)src)[0];
            float4 v1 = ((const float4*)src)[1];
            union { bf16x8 v; u16 u[8]; } pk;
            pk.u[0] = f2bf(v0.x); pk.u[1] = f2bf(v0.y); pk.u[2] = f2bf(v0.z); pk.u[3] = f2bf(v0.w);
            pk.u[4] = f2bf(v1.x); pk.u[5] = f2bf(v1.y); pk.u[6] = f2bf(v1.z); pk.u[7] = f2bf(v1.w);
            bfr[nf][kb] = pk.v;
        }

    f32x4 acc[2][4];
#pragma unroll
    for (int i = 0; i < 2; ++i)
#pragma unroll
        for (int j = 0; j < 4; ++j) acc[i][j] = f32x4{0.f, 0.f, 0.f, 0.f};

#pragma unroll
    for (int mf = 0; mf < 2; ++mf) {
        const int t = t0 + mf * 16 + (lane & 15);
        const u16* lrow = logits + ((size_t)b * 4096 + t) * 1024 + h * 64 + (lane >> 4) * 8;
        bf16x8 l0 = *(const bf16x8*)lrow;
        bf16x8 l1 = *(const bf16x8*)(lrow + 32);
        float va[16];
#pragma unroll
        for (int j = 0; j < 8; ++j) {
            va[j] = bf2f((u16)l0[j]) * 0.125f;
            va[8 + j] = bf2f((u16)l1[j]) * 0.125f;
        }
        float m = va[0];
#pragma unroll
        for (int j = 1; j < 16; ++j) m = fmaxf(m, va[j]);
        m = fmaxf(m, __shfl_xor(m, 16));
        m = fmaxf(m, __shfl_xor(m, 32));
        float sum = 0.f;
#pragma unroll
        for (int j = 0; j < 16; ++j) { va[j] = __expf(va[j] - m); sum += va[j]; }
        sum += __shfl_xor(sum, 16);
        sum += __shfl_xor(sum, 32);
        const float inv = 1.f / sum;
        union { bf16x8 v; u16 u[8]; } a0, a1;
#pragma unroll
        for (int j = 0; j < 8; ++j) {
            a0.u[j] = f2bf(va[j] * inv);
            a1.u[j] = f2bf(va[8 + j] * inv);
        }
#pragma unroll
        for (int nf = 0; nf < 4; ++nf) {
            acc[mf][nf] = __builtin_amdgcn_mfma_f32_16x16x32_bf16(a0.v, bfr[nf][0], acc[mf][nf], 0, 0, 0);
            acc[mf][nf] = __builtin_amdgcn_mfma_f32_16x16x32_bf16(a1.v, bfr[nf][1], acc[mf][nf], 0, 0, 0);
        }
    }

#pragma unroll
    for (int mf = 0; mf < 2; ++mf)
#pragma unroll
        for (int nf = 0; nf < 4; ++nf)
#pragma unroll
            for (int r = 0; r < 4; ++r) {
                int t = t0 + mf * 16 + (lane >> 4) * 4 + r;
                wout[((size_t)b * 4096 + t) * 1024 + h * 64 + nf * 16 + (lane & 15)] = f2bf(acc[mf][nf][r]);
            }
}

// ---------------- launch ----------------
extern "C" void kernel_launch(void* const* d_in, const int* in_sizes, int n_in,
                              void* d_out, int out_size, void* d_ws, size_t ws_size,
                              hipStream_t stream)
{
    const float* x  = (const float*)d_in[0];
    const float* lq = (const float*)d_in[1];
    const float* Wk = (const float*)d_in[2];
    const float* Wv = (const float*)d_in[3];
    const float* Wg = (const float*)d_in[4];
    const float* Wp = (const float*)d_in[5];

    char* ws = (char*)d_ws;
    u16*    wkv   = (u16*)(ws + 0);          //  4,194,304  [Wk;Wv] bf16 [2048][1024]
    u16*    wg    = (u16*)(ws + 4194304);    //  2,097,152
    u16*    wp    = (u16*)(ws + 6291456);    //  2,097,152
    float2* rope  = (float2*)(ws + 8388608); //  1,048,576
    float*  attnT = (float*)(ws + 9437184);  //  2,097,152  [B*H][64][64]
    u16*    kv    = (u16*)(ws + 11534336);   // 67,108,864  [16384][2048]; reused as wout
    u16* logits = (u16*)d_out;                       // [32768][1024] bf16
    u16* xb     = (u16*)((char*)d_out + 67108864);   // [32768][1024] bf16

    hipFuncSetAttribute((const void*)k_gemm256<0>, hipFuncAttributeMaxDynamicSharedMemorySize, 131072);
    hipFuncSetAttribute((const void*)k_gemm256<1>, hipFuncAttributeMaxDynamicSharedMemorySize, 131072);
    hipFuncSetAttribute((const void*)k_gemm256<2>, hipFuncAttributeMaxDynamicSharedMemorySize, 131072);

    hipMemsetAsync(attnT, 0, 128 * 4096 * sizeof(float), stream);

    k_cvt<<<2048, 256, 0, stream>>>(x, xb, 33554432 / 4);
    k_cvt<<<512, 256, 0, stream>>>(Wk, wkv, 1048576 / 4);
    k_cvt<<<512, 256, 0, stream>>>(Wv, wkv + 1048576, 1048576 / 4);
    k_cvt<<<512, 256, 0, stream>>>(Wg, wg, 1048576 / 4);
    k_cvt<<<512, 256, 0, stream>>>(Wp, wp, 1048576 / 4);
    k_rope<<<512, 256, 0, stream>>>(rope);

    // KV: M=16384 selected rows, N=2048
    k_gemm256<0><<<dim3(8, 64), 512, 131072, stream>>>(xb, wkv, kv, rope);
    // gate logits: M=32768, N=1024
    k_gemm256<1><<<dim3(4, 128), 512, 131072, stream>>>(xb, wg, logits, nullptr);
    // attention -> attnT
    k_attn<<<512, 256, 0, stream>>>(kv, lq, attnT);
    // weighted tokens (overwrites kv region)
    k_weighted<<<4096, 256, 0, stream>>>(logits, attnT, kv);
    // output projection -> d_out f32
    k_gemm256<2><<<dim3(4, 128), 512, 131072, stream>>>(kv, wp, d_out, nullptr);
}